// Round 9
// baseline (189.780 us; speedup 1.0000x reference)
//
#include <hip/hip_runtime.h>
#include <hip/hip_bf16.h>

#define IN_CH 48
#define OUT_CH 48
#define BN_EPS 1e-5f
#define CHUNK 4096          // edges per bin block
#define EPT   16            // edges per thread in bin role (CHUNK/256)
#define NPB   256           // nodes per bucket (bucket = dst >> 8)

__device__ __forceinline__ float bf2f(ushort u) {
    union { unsigned int i; float f; } v;
    v.i = ((unsigned int)u) << 16;
    return v.f;
}
__device__ __forceinline__ ushort f2bf(float f) {
    __hip_bfloat16 h = __float2bfloat16(f);  // round-to-nearest-even
    return *(ushort*)&h;
}

// ---------------------------------------------------------------------------
// k_zero: counts[N] = 0; block 0 also zeroes bhist[512] + stats[128]
// ---------------------------------------------------------------------------
__global__ __launch_bounds__(256) void k_zero(int* __restrict__ counts,
                                              int* __restrict__ bhist,
                                              float* __restrict__ stats, int N) {
    int t = threadIdx.x;
    int i = blockIdx.x * 256 + t;
    if (i < N) counts[i] = 0;
    if (blockIdx.x == 0) {
        bhist[t] = 0;
        bhist[t + 256] = 0;
        if (t < 128) stats[t] = 0.0f;
    }
}

// ---------------------------------------------------------------------------
// k_cnt: ONE pass over dst -> per-node counts (global atomics) + bucket
// histogram (LDS, flushed once). Replaces k_binhist and k_fine's hist pass.
// ---------------------------------------------------------------------------
__global__ __launch_bounds__(256) void k_cnt(const int* __restrict__ dst,
                                             int* __restrict__ counts,
                                             int* __restrict__ bhist, int E) {
    __shared__ int h[512];
    int t = threadIdx.x;
    h[t] = 0; h[t + 256] = 0;
    __syncthreads();
    for (int e = blockIdx.x * 256 + t; e < E; e += gridDim.x * 256) {
        int d = dst[e];
        atomicAdd(&counts[d], 1);
        atomicAdd(&h[d >> 8], 1);
    }
    __syncthreads();
    if (h[t]) atomicAdd(&bhist[t], h[t]);
    if (h[t + 256]) atomicAdd(&bhist[t + 256], h[t + 256]);
}

// ---------------------------------------------------------------------------
// k_scanb: exclusive scan of bhist[0..512) -> bstart[0..512], bcur = starts.
// ---------------------------------------------------------------------------
__global__ __launch_bounds__(256) void k_scanb(const int* __restrict__ bhist,
                                               int* __restrict__ bstart,
                                               int* __restrict__ bcur, int nb) {
    __shared__ int sc[256];
    int t = threadIdx.x;
    int i0 = 2 * t, i1 = 2 * t + 1;
    int a0 = bhist[i0];
    int a1 = bhist[i1];
    int ps = a0 + a1;
    sc[t] = ps;
    __syncthreads();
    for (int off = 1; off < 256; off <<= 1) {
        int v = (t >= off) ? sc[t - off] : 0;
        __syncthreads();
        sc[t] += v;
        __syncthreads();
    }
    int excl = sc[t] - ps;
    bstart[i0] = excl;
    bstart[i1] = excl + a0;
    if (i0 < nb) bcur[i0] = excl;
    if (i1 < nb) bcur[i1] = excl + a0;
    if (t == 255) bstart[512] = sc[255];  // == E
}

// ---------------------------------------------------------------------------
// k_binmm: role-split fusion. Blocks [0, nchunks) run the LDS counting-sort
// of a 4096-edge chunk (k_bin). Blocks [nchunks, nchunks+ngemm) run the
// node GEMM (k_gemm). Overlaps barrier-heavy sort with compute. LDS union'd.
// ---------------------------------------------------------------------------
union alignas(16) SMem {
    struct {
        int hist[512];
        int hbase[513];
        int sc[256];
        int gb[512];
        unsigned int stage[CHUNK];
        short stagebk[CHUNK];
    } bin;
    float Wl[IN_CH * OUT_CH];
};

__global__ __launch_bounds__(256) void k_binmm(const int* __restrict__ src,
                                               const int* __restrict__ dst,
                                               int* __restrict__ bcur,
                                               unsigned int* __restrict__ binned,
                                               int E, int nchunks,
                                               const float* __restrict__ x,
                                               const float* __restrict__ W,
                                               const int* __restrict__ counts,
                                               ushort* __restrict__ g, int N) {
    __shared__ SMem sm;
    int t = threadIdx.x;

    if (blockIdx.x < nchunks) {
        // ------------------- bin role -------------------
        int e0 = blockIdx.x * CHUNK;
        int n = min(CHUNK, E - e0);

        sm.bin.hist[t] = 0; sm.bin.hist[t + 256] = 0;
        __syncthreads();

        unsigned int w[EPT];
        short bb[EPT];
#pragma unroll
        for (int k = 0; k < EPT; ++k) {
            int i = t + k * 256;
            if (i < n) {
                int e = e0 + i;
                int s = src[e], d = dst[e];
                int b = d >> 8;
                w[k] = (unsigned int)s | ((unsigned int)(d & 255) << 17);
                bb[k] = (short)b;
                atomicAdd(&sm.bin.hist[b], 1);
            } else bb[k] = -1;
        }
        __syncthreads();
        int a0 = sm.bin.hist[2 * t], a1 = sm.bin.hist[2 * t + 1];
        int ps = a0 + a1;
        sm.bin.sc[t] = ps;
        __syncthreads();
        for (int off = 1; off < 256; off <<= 1) {
            int v = (t >= off) ? sm.bin.sc[t - off] : 0;
            __syncthreads();
            sm.bin.sc[t] += v;
            __syncthreads();
        }
        int excl = sm.bin.sc[t] - ps;
        sm.bin.hbase[2 * t] = excl;
        sm.bin.hbase[2 * t + 1] = excl + a0;
        if (t == 255) sm.bin.hbase[512] = sm.bin.sc[255];  // == n
        __syncthreads();
        sm.bin.hist[2 * t] = excl;            // cursors
        sm.bin.hist[2 * t + 1] = excl + a0;
        __syncthreads();
#pragma unroll
        for (int k = 0; k < EPT; ++k) {
            if (bb[k] >= 0) {
                int pos = atomicAdd(&sm.bin.hist[bb[k]], 1);
                sm.bin.stage[pos] = w[k];
                sm.bin.stagebk[pos] = bb[k];
            }
        }
        __syncthreads();
        for (int b = t; b < 512; b += 256) {
            int cnt = sm.bin.hbase[b + 1] - sm.bin.hbase[b];
            if (cnt > 0) sm.bin.gb[b] = atomicAdd(&bcur[b], cnt) - sm.bin.hbase[b];
        }
        __syncthreads();
        for (int j = t; j < n; j += 256) {
            int bk = sm.bin.stagebk[j];
            binned[sm.bin.gb[bk] + j] = sm.bin.stage[j];
        }
    } else {
        // ------------------- gemm role -------------------
        for (int idx = t; idx < IN_CH * OUT_CH / 4; idx += 256)
            ((float4*)sm.Wl)[idx] = ((const float4*)W)[idx];
        __syncthreads();

        int i = (blockIdx.x - nchunks) * 256 + t;
        if (i >= N) return;

        float xr[IN_CH];
        const float4* xp = (const float4*)(x + (size_t)i * IN_CH);
#pragma unroll
        for (int k = 0; k < IN_CH / 4; ++k) {
            float4 v = xp[k];
            xr[4 * k] = v.x; xr[4 * k + 1] = v.y; xr[4 * k + 2] = v.z; xr[4 * k + 3] = v.w;
        }
        float di = rsqrtf((float)counts[i] + 1.0f);

        ushort row[OUT_CH];
#pragma unroll
        for (int c4 = 0; c4 < OUT_CH / 4; ++c4) {
            float4 acc = make_float4(0.f, 0.f, 0.f, 0.f);
#pragma unroll
            for (int k = 0; k < IN_CH; ++k) {
                float4 wv = ((const float4*)sm.Wl)[k * (OUT_CH / 4) + c4];
                acc.x += xr[k] * wv.x; acc.y += xr[k] * wv.y;
                acc.z += xr[k] * wv.z; acc.w += xr[k] * wv.w;
            }
            row[4 * c4 + 0] = f2bf(acc.x * di);
            row[4 * c4 + 1] = f2bf(acc.y * di);
            row[4 * c4 + 2] = f2bf(acc.z * di);
            row[4 * c4 + 3] = f2bf(acc.w * di);
        }
        uint4* gp = (uint4*)(g + (size_t)i * OUT_CH);  // 96B row, 16B aligned
#pragma unroll
        for (int j = 0; j < 6; ++j) gp[j] = ((uint4*)row)[j];
    }
}

// ---------------------------------------------------------------------------
// k_fine: one block per bucket. Reads precomputed counts (NO histogram
// pass), scans, writes rowstart, single scatter pass binned -> sorted_src.
// ---------------------------------------------------------------------------
__global__ __launch_bounds__(512) void k_fine(const unsigned int* __restrict__ binned,
                                              const int* __restrict__ bstart,
                                              const int* __restrict__ counts,
                                              int* __restrict__ rowstart,
                                              int* __restrict__ sorted_src, int N) {
    __shared__ int sc[256];
    __shared__ int cur[256];
    int b = blockIdx.x, t = threadIdx.x;
    int node0 = b << 8;
    int nn = min(NPB, N - node0);
    int e0 = bstart[b], e1 = bstart[b + 1];
    int c = 0;
    if (t < 256) {
        c = (t < nn) ? counts[node0 + t] : 0;
        sc[t] = c;
    }
    __syncthreads();
    for (int off = 1; off < 256; off <<= 1) {
        int v = 0;
        if (t < 256 && t >= off) v = sc[t - off];
        __syncthreads();
        if (t < 256) sc[t] += v;
        __syncthreads();
    }
    if (t < 256) {
        int excl = sc[t] - c;
        cur[t] = e0 + excl;
        if (t < nn) rowstart[node0 + t] = e0 + excl;
    }
    __syncthreads();
    for (int e = e0 + t; e < e1; e += 512) {
        unsigned int w = binned[e];
        int dl = (int)(w >> 17);
        int pos = atomicAdd(&cur[dl], 1);
        sorted_src[pos] = (int)(w & 0x1ffff);
    }
}

// ---------------------------------------------------------------------------
// k_gather: one thread per (node, 4-channel group). uint2 loads (4 bf16),
// 12 lanes per row; float4 coalesced store. NO fused stats (round-7 lesson:
// 4688-block global-atomic epilogue on 96 addresses serialized at L2).
// ---------------------------------------------------------------------------
__global__ __launch_bounds__(256) void k_gather(const int* __restrict__ sorted_src,
                                                const int* __restrict__ rowstart,
                                                const int* __restrict__ counts,
                                                const ushort* __restrict__ g,
                                                float* __restrict__ out, int N) {
    int t = blockIdx.x * blockDim.x + threadIdx.x;
    if (t >= N * 12) return;
    int node = t / 12;
    int sub = t - node * 12;          // 0..11 -> channels [4*sub, 4*sub+4)
    const uint2* gp = (const uint2*)g;  // row = 12 x uint2 (8B each)
    int cnt = counts[node];
    int e = rowstart[node];
    int end = e + cnt;

    uint2 sv = gp[(size_t)node * 12 + sub];  // self loop
    float a0 = bf2f((ushort)(sv.x & 0xffff));
    float a1 = bf2f((ushort)(sv.x >> 16));
    float a2 = bf2f((ushort)(sv.y & 0xffff));
    float a3 = bf2f((ushort)(sv.y >> 16));

    for (; e + 4 <= end; e += 4) {
        int s0 = sorted_src[e];
        int s1 = sorted_src[e + 1];
        int s2 = sorted_src[e + 2];
        int s3 = sorted_src[e + 3];
        uint2 v0 = gp[(size_t)s0 * 12 + sub];
        uint2 v1 = gp[(size_t)s1 * 12 + sub];
        uint2 v2 = gp[(size_t)s2 * 12 + sub];
        uint2 v3 = gp[(size_t)s3 * 12 + sub];
        a0 += bf2f((ushort)(v0.x & 0xffff)) + bf2f((ushort)(v1.x & 0xffff))
            + bf2f((ushort)(v2.x & 0xffff)) + bf2f((ushort)(v3.x & 0xffff));
        a1 += bf2f((ushort)(v0.x >> 16)) + bf2f((ushort)(v1.x >> 16))
            + bf2f((ushort)(v2.x >> 16)) + bf2f((ushort)(v3.x >> 16));
        a2 += bf2f((ushort)(v0.y & 0xffff)) + bf2f((ushort)(v1.y & 0xffff))
            + bf2f((ushort)(v2.y & 0xffff)) + bf2f((ushort)(v3.y & 0xffff));
        a3 += bf2f((ushort)(v0.y >> 16)) + bf2f((ushort)(v1.y >> 16))
            + bf2f((ushort)(v2.y >> 16)) + bf2f((ushort)(v3.y >> 16));
    }
    for (; e < end; ++e) {
        int s = sorted_src[e];
        uint2 v = gp[(size_t)s * 12 + sub];
        a0 += bf2f((ushort)(v.x & 0xffff));
        a1 += bf2f((ushort)(v.x >> 16));
        a2 += bf2f((ushort)(v.y & 0xffff));
        a3 += bf2f((ushort)(v.y >> 16));
    }
    float di = rsqrtf((float)cnt + 1.0f);
    float4 r;
    r.x = a0 * di; r.y = a1 * di; r.z = a2 * di; r.w = a3 * di;
    ((float4*)out)[(size_t)node * 12 + sub] = r;
}

// ---------------------------------------------------------------------------
// k_stats: per-channel sum and sum-of-squares of out (256 blocks only)
// ---------------------------------------------------------------------------
__global__ __launch_bounds__(768) void k_stats(const float* __restrict__ v,
                                               float* __restrict__ stats, int N) {
    __shared__ float ls[16][OUT_CH];
    __shared__ float ls2[16][OUT_CH];
    int c = threadIdx.x;   // 0..47
    int ty = threadIdx.y;  // 0..15
    float s = 0.f, s2 = 0.f;
    for (int r = blockIdx.x * 16 + ty; r < N; r += gridDim.x * 16) {
        float u = v[(size_t)r * OUT_CH + c];
        s += u;
        s2 += u * u;
    }
    ls[ty][c] = s;
    ls2[ty][c] = s2;
    __syncthreads();
    for (int h = 8; h > 0; h >>= 1) {
        if (ty < h) {
            ls[ty][c] += ls[ty + h][c];
            ls2[ty][c] += ls2[ty + h][c];
        }
        __syncthreads();
    }
    if (ty == 0) {
        atomicAdd(&stats[c], ls[0][c]);
        atomicAdd(&stats[OUT_CH + c], ls2[0][c]);
    }
}

// ---------------------------------------------------------------------------
// k_final: BN (batch stats) + ReLU, in place. GCN bias b cancels under BN.
// ---------------------------------------------------------------------------
__global__ void k_final(float* __restrict__ out, const float* __restrict__ stats,
                        const float* __restrict__ gamma,
                        const float* __restrict__ beta, int N) {
    int t = blockIdx.x * blockDim.x + threadIdx.x;
    int total = N * OUT_CH;
    if (t >= total) return;
    int c = t % OUT_CH;
    float invN = 1.0f / (float)N;
    float m = stats[c] * invN;
    float var = stats[OUT_CH + c] * invN - m * m;
    float y = (out[t] - m) * rsqrtf(var + BN_EPS) * gamma[c] + beta[c];
    out[t] = fmaxf(y, 0.0f);
}

extern "C" void kernel_launch(void* const* d_in, const int* in_sizes, int n_in,
                              void* d_out, int out_size, void* d_ws, size_t ws_size,
                              hipStream_t stream) {
    const float* x     = (const float*)d_in[0];
    const int*   ei    = (const int*)d_in[1];
    const float* W     = (const float*)d_in[2];
    // d_in[3] = b : constant per-channel offset cancels in BatchNorm -> unused
    const float* gamma = (const float*)d_in[4];
    const float* beta  = (const float*)d_in[5];
    float*       out   = (float*)d_out;

    int N = in_sizes[0] / IN_CH;     // 100000 (< 2^17 for packing)
    int E = in_sizes[1] / 2;         // 1600000
    const int* src = ei;             // edge_index[0]
    const int* dst = ei + E;         // edge_index[1]

    int nb = (N + NPB - 1) / NPB;    // 391 buckets

    // workspace layout (bytes):
    // [0, 2048)       bhist int[512]
    // [2048, 2560)    stats float[128]
    // [2560, 4640)    bstart int[520]
    // [4640, 6688)    bcur int[512]
    // [8192, +4N)     counts int[N]
    // [.., +4N)       rowstart int[N]
    // [.., +4E)       binned uint[E]
    // [.., +4E)       sorted_src int[E]
    // [.., +96N)      g bf16[N*48] (16B aligned)
    char* wsb = (char*)d_ws;
    int*          bhist      = (int*)wsb;
    float*        stats      = (float*)(wsb + 2048);
    int*          bstart     = (int*)(wsb + 2560);
    int*          bcur       = (int*)(wsb + 4640);
    int*          counts     = (int*)(wsb + 8192);
    int*          rowstart   = (int*)(wsb + 8192 + (size_t)4 * N);
    unsigned int* binned     = (unsigned int*)(wsb + 8192 + (size_t)8 * N);
    int*          sorted_src = (int*)(wsb + 8192 + (size_t)8 * N + (size_t)4 * E);
    ushort*       g          = (ushort*)(wsb + 8192 + (size_t)8 * N + (size_t)8 * E);

    int b = 256;
    int nzero = (N + b - 1) / b;          // 391
    int nchunks = (E + CHUNK - 1) / CHUNK;  // 391
    int ngemm = (N + b - 1) / b;          // 391

    // 1. zero counts + bhist + stats
    k_zero<<<nzero, b, 0, stream>>>(counts, bhist, stats, N);
    // 2. fused per-node counts + bucket histogram (one pass over dst)
    k_cnt<<<512, b, 0, stream>>>(dst, counts, bhist, E);
    // 3. bucket scan -> bstart / bcur
    k_scanb<<<1, b, 0, stream>>>(bhist, bstart, bcur, nb);
    // 4. fused: coarse counting-sort (blocks 0..nchunks) + GEMM (rest)
    k_binmm<<<nchunks + ngemm, b, 0, stream>>>(src, dst, bcur, binned, E, nchunks,
                                               x, W, counts, g, N);
    // 5. fine sort within buckets (counts-driven, single pass)
    k_fine<<<nb, 512, 0, stream>>>(binned, bstart, counts, rowstart, sorted_src, N);
    // 6. gather + self loop + dst dinv (4 channels per thread)
    int gthreads = N * 12;
    k_gather<<<(gthreads + b - 1) / b, b, 0, stream>>>(sorted_src, rowstart, counts, g, out, N);
    // 7. BN stats
    dim3 sblk(OUT_CH, 16);
    k_stats<<<256, sblk, 0, stream>>>(out, stats, N);
    // 8. BN + ReLU in place
    int totalT = N * OUT_CH;
    k_final<<<(totalT + b - 1) / b, b, 0, stream>>>(out, stats, gamma, beta, N);
}

// Round 10
// 144.419 us; speedup vs baseline: 1.3141x; 1.3141x over previous
//
#include <hip/hip_runtime.h>
#include <hip/hip_bf16.h>

#define IN_CH 48
#define OUT_CH 48
#define BN_EPS 1e-5f
#define CHUNK 4096          // edges per bin block
#define EPT   16            // edges per thread in bin role (CHUNK/256)
#define NPB   256           // nodes per bucket (bucket = dst >> 8)
#define NHB   64            // histogram blocks (partial, non-atomic)

__device__ __forceinline__ float bf2f(ushort u) {
    union { unsigned int i; float f; } v;
    v.i = ((unsigned int)u) << 16;
    return v.f;
}
__device__ __forceinline__ ushort f2bf(float f) {
    __hip_bfloat16 h = __float2bfloat16(f);  // round-to-nearest-even
    return *(ushort*)&h;
}

// ---------------------------------------------------------------------------
// k_binhist: 64 blocks, per-block LDS bucket hist over a grid-stride slice,
// written as NON-atomic partials bpart[blk][512]. No pre-zero needed.
// ---------------------------------------------------------------------------
__global__ __launch_bounds__(256) void k_binhist(const int* __restrict__ dst,
                                                 int* __restrict__ bpart, int E) {
    __shared__ int h[512];
    int t = threadIdx.x;
    h[t] = 0; h[t + 256] = 0;
    __syncthreads();
    for (int e = blockIdx.x * 256 + t; e < E; e += NHB * 256)
        atomicAdd(&h[dst[e] >> 8], 1);
    __syncthreads();
    bpart[blockIdx.x * 512 + t] = h[t];
    bpart[blockIdx.x * 512 + t + 256] = h[t + 256];
}

// ---------------------------------------------------------------------------
// k_scanb: reduce 64 partials -> bucket totals, exclusive scan -> bstart,
// bcur. Also zeroes stats[128].
// ---------------------------------------------------------------------------
__global__ __launch_bounds__(256) void k_scanb(const int* __restrict__ bpart,
                                               int* __restrict__ bstart,
                                               int* __restrict__ bcur, int nb,
                                               float* __restrict__ stats) {
    __shared__ int sc[256];
    int t = threadIdx.x;
    if (t < 128) stats[t] = 0.0f;
    int i0 = 2 * t, i1 = 2 * t + 1;
    int a0 = 0, a1 = 0;
    for (int blk = 0; blk < NHB; ++blk) {
        a0 += bpart[blk * 512 + i0];
        a1 += bpart[blk * 512 + i1];
    }
    int ps = a0 + a1;
    sc[t] = ps;
    __syncthreads();
    for (int off = 1; off < 256; off <<= 1) {
        int v = (t >= off) ? sc[t - off] : 0;
        __syncthreads();
        sc[t] += v;
        __syncthreads();
    }
    int excl = sc[t] - ps;
    bstart[i0] = excl;
    bstart[i1] = excl + a0;
    if (i0 < nb) bcur[i0] = excl;
    if (i1 < nb) bcur[i1] = excl + a0;
    if (t == 255) bstart[512] = sc[255];  // == E
}

// ---------------------------------------------------------------------------
// k_binmm: role-split fusion. Blocks [0, nchunks): LDS counting-sort of a
// 4096-edge chunk. Blocks [nchunks, ..): UNSCALED node GEMM g = bf16(x@W)
// (dinv applied later in k_fine once counts exist). LDS union'd.
// ---------------------------------------------------------------------------
union alignas(16) SMem {
    struct {
        int hist[512];
        int hbase[513];
        int sc[256];
        int gb[512];
        unsigned int stage[CHUNK];
        short stagebk[CHUNK];
    } bin;
    float Wl[IN_CH * OUT_CH];
};

__global__ __launch_bounds__(256) void k_binmm(const int* __restrict__ src,
                                               const int* __restrict__ dst,
                                               int* __restrict__ bcur,
                                               unsigned int* __restrict__ binned,
                                               int E, int nchunks,
                                               const float* __restrict__ x,
                                               const float* __restrict__ W,
                                               ushort* __restrict__ g, int N) {
    __shared__ SMem sm;
    int t = threadIdx.x;

    if (blockIdx.x < nchunks) {
        // ------------------- bin role -------------------
        int e0 = blockIdx.x * CHUNK;
        int n = min(CHUNK, E - e0);

        sm.bin.hist[t] = 0; sm.bin.hist[t + 256] = 0;
        __syncthreads();

        unsigned int w[EPT];
        short bb[EPT];
#pragma unroll
        for (int k = 0; k < EPT; ++k) {
            int i = t + k * 256;
            if (i < n) {
                int e = e0 + i;
                int s = src[e], d = dst[e];
                int b = d >> 8;
                w[k] = (unsigned int)s | ((unsigned int)(d & 255) << 17);
                bb[k] = (short)b;
                atomicAdd(&sm.bin.hist[b], 1);
            } else bb[k] = -1;
        }
        __syncthreads();
        int a0 = sm.bin.hist[2 * t], a1 = sm.bin.hist[2 * t + 1];
        int ps = a0 + a1;
        sm.bin.sc[t] = ps;
        __syncthreads();
        for (int off = 1; off < 256; off <<= 1) {
            int v = (t >= off) ? sm.bin.sc[t - off] : 0;
            __syncthreads();
            sm.bin.sc[t] += v;
            __syncthreads();
        }
        int excl = sm.bin.sc[t] - ps;
        sm.bin.hbase[2 * t] = excl;
        sm.bin.hbase[2 * t + 1] = excl + a0;
        if (t == 255) sm.bin.hbase[512] = sm.bin.sc[255];  // == n
        __syncthreads();
        sm.bin.hist[2 * t] = excl;            // cursors
        sm.bin.hist[2 * t + 1] = excl + a0;
        __syncthreads();
#pragma unroll
        for (int k = 0; k < EPT; ++k) {
            if (bb[k] >= 0) {
                int pos = atomicAdd(&sm.bin.hist[bb[k]], 1);
                sm.bin.stage[pos] = w[k];
                sm.bin.stagebk[pos] = bb[k];
            }
        }
        __syncthreads();
        for (int b = t; b < 512; b += 256) {
            int cnt = sm.bin.hbase[b + 1] - sm.bin.hbase[b];
            if (cnt > 0) sm.bin.gb[b] = atomicAdd(&bcur[b], cnt) - sm.bin.hbase[b];
        }
        __syncthreads();
        for (int j = t; j < n; j += 256) {
            int bk = sm.bin.stagebk[j];
            binned[sm.bin.gb[bk] + j] = sm.bin.stage[j];
        }
    } else {
        // ------------------- gemm role (unscaled) -------------------
        for (int idx = t; idx < IN_CH * OUT_CH / 4; idx += 256)
            ((float4*)sm.Wl)[idx] = ((const float4*)W)[idx];
        __syncthreads();

        int i = (blockIdx.x - nchunks) * 256 + t;
        if (i >= N) return;

        float xr[IN_CH];
        const float4* xp = (const float4*)(x + (size_t)i * IN_CH);
#pragma unroll
        for (int k = 0; k < IN_CH / 4; ++k) {
            float4 v = xp[k];
            xr[4 * k] = v.x; xr[4 * k + 1] = v.y; xr[4 * k + 2] = v.z; xr[4 * k + 3] = v.w;
        }

        ushort row[OUT_CH];
#pragma unroll
        for (int c4 = 0; c4 < OUT_CH / 4; ++c4) {
            float4 acc = make_float4(0.f, 0.f, 0.f, 0.f);
#pragma unroll
            for (int k = 0; k < IN_CH; ++k) {
                float4 wv = ((const float4*)sm.Wl)[k * (OUT_CH / 4) + c4];
                acc.x += xr[k] * wv.x; acc.y += xr[k] * wv.y;
                acc.z += xr[k] * wv.z; acc.w += xr[k] * wv.w;
            }
            row[4 * c4 + 0] = f2bf(acc.x);
            row[4 * c4 + 1] = f2bf(acc.y);
            row[4 * c4 + 2] = f2bf(acc.z);
            row[4 * c4 + 3] = f2bf(acc.w);
        }
        uint4* gp = (uint4*)(g + (size_t)i * OUT_CH);  // 96B row, 16B aligned
#pragma unroll
        for (int j = 0; j < 6; ++j) gp[j] = ((uint4*)row)[j];
    }
}

// ---------------------------------------------------------------------------
// k_fine: one block per bucket. LDS hist over binned -> counts + rowstart,
// scatter src ids into the bucket's contiguous window, then RESCALE the
// bucket's g rows by dinv (counts live in LDS; 24KB/block coalesced).
// ---------------------------------------------------------------------------
__global__ __launch_bounds__(512) void k_fine(const unsigned int* __restrict__ binned,
                                              const int* __restrict__ bstart,
                                              int* __restrict__ counts,
                                              int* __restrict__ rowstart,
                                              int* __restrict__ sorted_src,
                                              ushort* __restrict__ g, int N) {
    __shared__ int cnt[256];
    __shared__ int sc[256];
    __shared__ int cur[256];
    __shared__ float sdinv[256];
    int b = blockIdx.x, t = threadIdx.x;
    int node0 = b << 8;
    int nn = min(NPB, N - node0);
    if (t < 256) cnt[t] = 0;
    __syncthreads();
    int e0 = bstart[b], e1 = bstart[b + 1];
    for (int e = e0 + t; e < e1; e += 512)
        atomicAdd(&cnt[binned[e] >> 17], 1);
    __syncthreads();
    if (t < 256) sc[t] = cnt[t];
    __syncthreads();
    for (int off = 1; off < 256; off <<= 1) {
        int v = 0;
        if (t < 256 && t >= off) v = sc[t - off];
        __syncthreads();
        if (t < 256) sc[t] += v;
        __syncthreads();
    }
    if (t < 256) {
        int excl = sc[t] - cnt[t];
        cur[t] = e0 + excl;
        sdinv[t] = rsqrtf((float)cnt[t] + 1.0f);
        if (t < nn) {
            counts[node0 + t] = cnt[t];
            rowstart[node0 + t] = e0 + excl;
        }
    }
    __syncthreads();
    for (int e = e0 + t; e < e1; e += 512) {
        unsigned int w = binned[e];
        int dl = (int)(w >> 17);
        int pos = atomicAdd(&cur[dl], 1);
        sorted_src[pos] = (int)(w & 0x1ffff);
    }
    // rescale this bucket's g rows: g[node] *= dinv[node]
    unsigned int* gw = (unsigned int*)(g + (size_t)node0 * OUT_CH);
    int words = nn * (OUT_CH / 2);  // 24 words per row
    for (int i = t; i < words; i += 512) {
        int r = i / (OUT_CH / 2);
        float d = sdinv[r];
        unsigned int u = gw[i];
        float lo = bf2f((ushort)(u & 0xffff)) * d;
        float hi = bf2f((ushort)(u >> 16)) * d;
        gw[i] = (unsigned int)f2bf(lo) | ((unsigned int)f2bf(hi) << 16);
    }
}

// ---------------------------------------------------------------------------
// k_gather: one thread per (node, 4-channel group). uint2 loads (4 bf16),
// 12 lanes per row; float4 coalesced store. NO fused stats (round-7 lesson).
// ---------------------------------------------------------------------------
__global__ __launch_bounds__(256) void k_gather(const int* __restrict__ sorted_src,
                                                const int* __restrict__ rowstart,
                                                const int* __restrict__ counts,
                                                const ushort* __restrict__ g,
                                                float* __restrict__ out, int N) {
    int t = blockIdx.x * blockDim.x + threadIdx.x;
    if (t >= N * 12) return;
    int node = t / 12;
    int sub = t - node * 12;          // 0..11 -> channels [4*sub, 4*sub+4)
    const uint2* gp = (const uint2*)g;  // row = 12 x uint2 (8B each)
    int cnt = counts[node];
    int e = rowstart[node];
    int end = e + cnt;

    uint2 sv = gp[(size_t)node * 12 + sub];  // self loop
    float a0 = bf2f((ushort)(sv.x & 0xffff));
    float a1 = bf2f((ushort)(sv.x >> 16));
    float a2 = bf2f((ushort)(sv.y & 0xffff));
    float a3 = bf2f((ushort)(sv.y >> 16));

    for (; e + 4 <= end; e += 4) {
        int s0 = sorted_src[e];
        int s1 = sorted_src[e + 1];
        int s2 = sorted_src[e + 2];
        int s3 = sorted_src[e + 3];
        uint2 v0 = gp[(size_t)s0 * 12 + sub];
        uint2 v1 = gp[(size_t)s1 * 12 + sub];
        uint2 v2 = gp[(size_t)s2 * 12 + sub];
        uint2 v3 = gp[(size_t)s3 * 12 + sub];
        a0 += bf2f((ushort)(v0.x & 0xffff)) + bf2f((ushort)(v1.x & 0xffff))
            + bf2f((ushort)(v2.x & 0xffff)) + bf2f((ushort)(v3.x & 0xffff));
        a1 += bf2f((ushort)(v0.x >> 16)) + bf2f((ushort)(v1.x >> 16))
            + bf2f((ushort)(v2.x >> 16)) + bf2f((ushort)(v3.x >> 16));
        a2 += bf2f((ushort)(v0.y & 0xffff)) + bf2f((ushort)(v1.y & 0xffff))
            + bf2f((ushort)(v2.y & 0xffff)) + bf2f((ushort)(v3.y & 0xffff));
        a3 += bf2f((ushort)(v0.y >> 16)) + bf2f((ushort)(v1.y >> 16))
            + bf2f((ushort)(v2.y >> 16)) + bf2f((ushort)(v3.y >> 16));
    }
    for (; e < end; ++e) {
        int s = sorted_src[e];
        uint2 v = gp[(size_t)s * 12 + sub];
        a0 += bf2f((ushort)(v.x & 0xffff));
        a1 += bf2f((ushort)(v.x >> 16));
        a2 += bf2f((ushort)(v.y & 0xffff));
        a3 += bf2f((ushort)(v.y >> 16));
    }
    float di = rsqrtf((float)cnt + 1.0f);
    float4 r;
    r.x = a0 * di; r.y = a1 * di; r.z = a2 * di; r.w = a3 * di;
    ((float4*)out)[(size_t)node * 12 + sub] = r;
}

// ---------------------------------------------------------------------------
// k_stats: per-channel sum and sum-of-squares of out (256 blocks only)
// ---------------------------------------------------------------------------
__global__ __launch_bounds__(768) void k_stats(const float* __restrict__ v,
                                               float* __restrict__ stats, int N) {
    __shared__ float ls[16][OUT_CH];
    __shared__ float ls2[16][OUT_CH];
    int c = threadIdx.x;   // 0..47
    int ty = threadIdx.y;  // 0..15
    float s = 0.f, s2 = 0.f;
    for (int r = blockIdx.x * 16 + ty; r < N; r += gridDim.x * 16) {
        float u = v[(size_t)r * OUT_CH + c];
        s += u;
        s2 += u * u;
    }
    ls[ty][c] = s;
    ls2[ty][c] = s2;
    __syncthreads();
    for (int h = 8; h > 0; h >>= 1) {
        if (ty < h) {
            ls[ty][c] += ls[ty + h][c];
            ls2[ty][c] += ls2[ty + h][c];
        }
        __syncthreads();
    }
    if (ty == 0) {
        atomicAdd(&stats[c], ls[0][c]);
        atomicAdd(&stats[OUT_CH + c], ls2[0][c]);
    }
}

// ---------------------------------------------------------------------------
// k_final: BN (batch stats) + ReLU, in place. GCN bias b cancels under BN.
// ---------------------------------------------------------------------------
__global__ void k_final(float* __restrict__ out, const float* __restrict__ stats,
                        const float* __restrict__ gamma,
                        const float* __restrict__ beta, int N) {
    int t = blockIdx.x * blockDim.x + threadIdx.x;
    int total = N * OUT_CH;
    if (t >= total) return;
    int c = t % OUT_CH;
    float invN = 1.0f / (float)N;
    float m = stats[c] * invN;
    float var = stats[OUT_CH + c] * invN - m * m;
    float y = (out[t] - m) * rsqrtf(var + BN_EPS) * gamma[c] + beta[c];
    out[t] = fmaxf(y, 0.0f);
}

extern "C" void kernel_launch(void* const* d_in, const int* in_sizes, int n_in,
                              void* d_out, int out_size, void* d_ws, size_t ws_size,
                              hipStream_t stream) {
    const float* x     = (const float*)d_in[0];
    const int*   ei    = (const int*)d_in[1];
    const float* W     = (const float*)d_in[2];
    // d_in[3] = b : constant per-channel offset cancels in BatchNorm -> unused
    const float* gamma = (const float*)d_in[4];
    const float* beta  = (const float*)d_in[5];
    float*       out   = (float*)d_out;

    int N = in_sizes[0] / IN_CH;     // 100000 (< 2^17 for packing)
    int E = in_sizes[1] / 2;         // 1600000
    const int* src = ei;             // edge_index[0]
    const int* dst = ei + E;         // edge_index[1]

    int nb = (N + NPB - 1) / NPB;    // 391 buckets

    // workspace layout (bytes):
    // [0, 512)          stats float[128]
    // [512, 2564)       bstart int[513]
    // [4096, 6144)      bcur int[512]
    // [8192, 139264)    bpart int[64*512]
    // [139264, +4N)     counts int[N]
    // [.., +4N)         rowstart int[N]
    // [.., +4E)         binned uint[E]
    // [.., +4E)         sorted_src int[E]
    // [.., +96N)        g bf16[N*48] (16B aligned)
    char* wsb = (char*)d_ws;
    float*        stats      = (float*)wsb;
    int*          bstart     = (int*)(wsb + 512);
    int*          bcur       = (int*)(wsb + 4096);
    int*          bpart      = (int*)(wsb + 8192);
    size_t A = 8192 + (size_t)NHB * 512 * 4;  // 139264
    int*          counts     = (int*)(wsb + A);
    int*          rowstart   = (int*)(wsb + A + (size_t)4 * N);
    unsigned int* binned     = (unsigned int*)(wsb + A + (size_t)8 * N);
    int*          sorted_src = (int*)(wsb + A + (size_t)8 * N + (size_t)4 * E);
    ushort*       g          = (ushort*)(wsb + A + (size_t)8 * N + (size_t)8 * E);

    int b = 256;
    int nchunks = (E + CHUNK - 1) / CHUNK;   // 391
    int ngemm = (N + b - 1) / b;             // 391

    // 1. bucket histogram partials (no atomics, no pre-zero)
    k_binhist<<<NHB, b, 0, stream>>>(dst, bpart, E);
    // 2. reduce + scan -> bstart / bcur; zero stats
    k_scanb<<<1, b, 0, stream>>>(bpart, bstart, bcur, nb, stats);
    // 3. fused: coarse counting-sort (blocks 0..nchunks) + unscaled GEMM (rest)
    k_binmm<<<nchunks + ngemm, b, 0, stream>>>(src, dst, bcur, binned, E, nchunks,
                                               x, W, g, N);
    // 4. fine sort within buckets -> counts/rowstart/sorted_src + g rescale
    k_fine<<<nb, 512, 0, stream>>>(binned, bstart, counts, rowstart, sorted_src, g, N);
    // 5. gather + self loop + dst dinv (4 channels per thread)
    int gthreads = N * 12;
    k_gather<<<(gthreads + b - 1) / b, b, 0, stream>>>(sorted_src, rowstart, counts, g, out, N);
    // 6. BN stats
    dim3 sblk(OUT_CH, 16);
    k_stats<<<256, sblk, 0, stream>>>(out, stats, N);
    // 7. BN + ReLU in place
    int totalT = N * OUT_CH;
    k_final<<<(totalT + b - 1) / b, b, 0, stream>>>(out, stats, gamma, beta, N);
}

// Round 11
// 130.138 us; speedup vs baseline: 1.4583x; 1.1097x over previous
//
#include <hip/hip_runtime.h>
#include <hip/hip_bf16.h>

#define IN_CH 48
#define OUT_CH 48
#define BN_EPS 1e-5f
#define CHUNK 4096          // edges per bin block
#define EPT   16            // edges per thread in bin role (CHUNK/256)
#define NPB   256           // nodes per bucket (bucket = dst >> 8)
#define NHB   512           // histogram blocks

__device__ __forceinline__ float bf2f(ushort u) {
    union { unsigned int i; float f; } v;
    v.i = ((unsigned int)u) << 16;
    return v.f;
}
__device__ __forceinline__ ushort f2bf(float f) {
    __hip_bfloat16 h = __float2bfloat16(f);  // round-to-nearest-even
    return *(ushort*)&h;
}

// ---------------------------------------------------------------------------
// k_zero: bhist[512] = 0 (1 block; stats zeroed inside k_scanb)
// ---------------------------------------------------------------------------
__global__ __launch_bounds__(512) void k_zero(int* __restrict__ bhist) {
    bhist[threadIdx.x] = 0;
}

// ---------------------------------------------------------------------------
// k_binhist: 512 blocks, LDS bucket hist over grid-stride slice, flushed
// with global atomics. Unroll-4 breaks the load->atomic dependency chain
// (round-10 lesson: 64-block version serialized on load latency, 43us).
// ---------------------------------------------------------------------------
__global__ __launch_bounds__(256) void k_binhist(const int* __restrict__ dst,
                                                 int* __restrict__ bhist, int E) {
    __shared__ int h[512];
    int t = threadIdx.x;
    h[t] = 0; h[t + 256] = 0;
    __syncthreads();
    const int stride = NHB * 256;
    int e = blockIdx.x * 256 + t;
    for (; e + 3 * stride < E; e += 4 * stride) {
        int d0 = dst[e];
        int d1 = dst[e + stride];
        int d2 = dst[e + 2 * stride];
        int d3 = dst[e + 3 * stride];
        atomicAdd(&h[d0 >> 8], 1);
        atomicAdd(&h[d1 >> 8], 1);
        atomicAdd(&h[d2 >> 8], 1);
        atomicAdd(&h[d3 >> 8], 1);
    }
    for (; e < E; e += stride) atomicAdd(&h[dst[e] >> 8], 1);
    __syncthreads();
    if (h[t]) atomicAdd(&bhist[t], h[t]);
    if (h[t + 256]) atomicAdd(&bhist[t + 256], h[t + 256]);
}

// ---------------------------------------------------------------------------
// k_scanb: exclusive scan of bhist -> bstart, bcur. Zeroes stats[128].
// ---------------------------------------------------------------------------
__global__ __launch_bounds__(256) void k_scanb(const int* __restrict__ bhist,
                                               int* __restrict__ bstart,
                                               int* __restrict__ bcur, int nb,
                                               float* __restrict__ stats) {
    __shared__ int sc[256];
    int t = threadIdx.x;
    if (t < 128) stats[t] = 0.0f;
    int i0 = 2 * t, i1 = 2 * t + 1;
    int a0 = bhist[i0];
    int a1 = bhist[i1];
    int ps = a0 + a1;
    sc[t] = ps;
    __syncthreads();
    for (int off = 1; off < 256; off <<= 1) {
        int v = (t >= off) ? sc[t - off] : 0;
        __syncthreads();
        sc[t] += v;
        __syncthreads();
    }
    int excl = sc[t] - ps;
    bstart[i0] = excl;
    bstart[i1] = excl + a0;
    if (i0 < nb) bcur[i0] = excl;
    if (i1 < nb) bcur[i1] = excl + a0;
    if (t == 255) bstart[512] = sc[255];  // == E
}

// ---------------------------------------------------------------------------
// k_binmm: role-split fusion. Blocks [0, nchunks): LDS counting-sort of a
// 4096-edge chunk. Blocks [nchunks, ..): UNSCALED node GEMM g = bf16(x@W)
// (dinv applied later in k_fine once counts exist). LDS union'd.
// ---------------------------------------------------------------------------
union alignas(16) SMem {
    struct {
        int hist[512];
        int hbase[513];
        int sc[256];
        int gb[512];
        unsigned int stage[CHUNK];
        short stagebk[CHUNK];
    } bin;
    float Wl[IN_CH * OUT_CH];
};

__global__ __launch_bounds__(256) void k_binmm(const int* __restrict__ src,
                                               const int* __restrict__ dst,
                                               int* __restrict__ bcur,
                                               unsigned int* __restrict__ binned,
                                               int E, int nchunks,
                                               const float* __restrict__ x,
                                               const float* __restrict__ W,
                                               ushort* __restrict__ g, int N) {
    __shared__ SMem sm;
    int t = threadIdx.x;

    if (blockIdx.x < nchunks) {
        // ------------------- bin role -------------------
        int e0 = blockIdx.x * CHUNK;
        int n = min(CHUNK, E - e0);

        sm.bin.hist[t] = 0; sm.bin.hist[t + 256] = 0;
        __syncthreads();

        unsigned int w[EPT];
        short bb[EPT];
#pragma unroll
        for (int k = 0; k < EPT; ++k) {
            int i = t + k * 256;
            if (i < n) {
                int e = e0 + i;
                int s = src[e], d = dst[e];
                int b = d >> 8;
                w[k] = (unsigned int)s | ((unsigned int)(d & 255) << 17);
                bb[k] = (short)b;
                atomicAdd(&sm.bin.hist[b], 1);
            } else bb[k] = -1;
        }
        __syncthreads();
        int a0 = sm.bin.hist[2 * t], a1 = sm.bin.hist[2 * t + 1];
        int ps = a0 + a1;
        sm.bin.sc[t] = ps;
        __syncthreads();
        for (int off = 1; off < 256; off <<= 1) {
            int v = (t >= off) ? sm.bin.sc[t - off] : 0;
            __syncthreads();
            sm.bin.sc[t] += v;
            __syncthreads();
        }
        int excl = sm.bin.sc[t] - ps;
        sm.bin.hbase[2 * t] = excl;
        sm.bin.hbase[2 * t + 1] = excl + a0;
        if (t == 255) sm.bin.hbase[512] = sm.bin.sc[255];  // == n
        __syncthreads();
        sm.bin.hist[2 * t] = excl;            // cursors
        sm.bin.hist[2 * t + 1] = excl + a0;
        __syncthreads();
#pragma unroll
        for (int k = 0; k < EPT; ++k) {
            if (bb[k] >= 0) {
                int pos = atomicAdd(&sm.bin.hist[bb[k]], 1);
                sm.bin.stage[pos] = w[k];
                sm.bin.stagebk[pos] = bb[k];
            }
        }
        __syncthreads();
        for (int b = t; b < 512; b += 256) {
            int cnt = sm.bin.hbase[b + 1] - sm.bin.hbase[b];
            if (cnt > 0) sm.bin.gb[b] = atomicAdd(&bcur[b], cnt) - sm.bin.hbase[b];
        }
        __syncthreads();
        for (int j = t; j < n; j += 256) {
            int bk = sm.bin.stagebk[j];
            binned[sm.bin.gb[bk] + j] = sm.bin.stage[j];
        }
    } else {
        // ------------------- gemm role (unscaled) -------------------
        for (int idx = t; idx < IN_CH * OUT_CH / 4; idx += 256)
            ((float4*)sm.Wl)[idx] = ((const float4*)W)[idx];
        __syncthreads();

        int i = (blockIdx.x - nchunks) * 256 + t;
        if (i >= N) return;

        float xr[IN_CH];
        const float4* xp = (const float4*)(x + (size_t)i * IN_CH);
#pragma unroll
        for (int k = 0; k < IN_CH / 4; ++k) {
            float4 v = xp[k];
            xr[4 * k] = v.x; xr[4 * k + 1] = v.y; xr[4 * k + 2] = v.z; xr[4 * k + 3] = v.w;
        }

        ushort row[OUT_CH];
#pragma unroll
        for (int c4 = 0; c4 < OUT_CH / 4; ++c4) {
            float4 acc = make_float4(0.f, 0.f, 0.f, 0.f);
#pragma unroll
            for (int k = 0; k < IN_CH; ++k) {
                float4 wv = ((const float4*)sm.Wl)[k * (OUT_CH / 4) + c4];
                acc.x += xr[k] * wv.x; acc.y += xr[k] * wv.y;
                acc.z += xr[k] * wv.z; acc.w += xr[k] * wv.w;
            }
            row[4 * c4 + 0] = f2bf(acc.x);
            row[4 * c4 + 1] = f2bf(acc.y);
            row[4 * c4 + 2] = f2bf(acc.z);
            row[4 * c4 + 3] = f2bf(acc.w);
        }
        uint4* gp = (uint4*)(g + (size_t)i * OUT_CH);  // 96B row, 16B aligned
#pragma unroll
        for (int j = 0; j < 6; ++j) gp[j] = ((uint4*)row)[j];
    }
}

// ---------------------------------------------------------------------------
// k_fine: one block per bucket. LDS hist over binned -> counts + rowstart,
// scatter src ids into the bucket's contiguous window, then RESCALE the
// bucket's g rows by dinv (counts live in LDS; 24KB/block coalesced).
// ---------------------------------------------------------------------------
__global__ __launch_bounds__(512) void k_fine(const unsigned int* __restrict__ binned,
                                              const int* __restrict__ bstart,
                                              int* __restrict__ counts,
                                              int* __restrict__ rowstart,
                                              int* __restrict__ sorted_src,
                                              ushort* __restrict__ g, int N) {
    __shared__ int cnt[256];
    __shared__ int sc[256];
    __shared__ int cur[256];
    __shared__ float sdinv[256];
    int b = blockIdx.x, t = threadIdx.x;
    int node0 = b << 8;
    int nn = min(NPB, N - node0);
    if (t < 256) cnt[t] = 0;
    __syncthreads();
    int e0 = bstart[b], e1 = bstart[b + 1];
    for (int e = e0 + t; e < e1; e += 512)
        atomicAdd(&cnt[binned[e] >> 17], 1);
    __syncthreads();
    if (t < 256) sc[t] = cnt[t];
    __syncthreads();
    for (int off = 1; off < 256; off <<= 1) {
        int v = 0;
        if (t < 256 && t >= off) v = sc[t - off];
        __syncthreads();
        if (t < 256) sc[t] += v;
        __syncthreads();
    }
    if (t < 256) {
        int excl = sc[t] - cnt[t];
        cur[t] = e0 + excl;
        sdinv[t] = rsqrtf((float)cnt[t] + 1.0f);
        if (t < nn) {
            counts[node0 + t] = cnt[t];
            rowstart[node0 + t] = e0 + excl;
        }
    }
    __syncthreads();
    for (int e = e0 + t; e < e1; e += 512) {
        unsigned int w = binned[e];
        int dl = (int)(w >> 17);
        int pos = atomicAdd(&cur[dl], 1);
        sorted_src[pos] = (int)(w & 0x1ffff);
    }
    // rescale this bucket's g rows: g[node] *= dinv[node]
    unsigned int* gw = (unsigned int*)(g + (size_t)node0 * OUT_CH);
    int words = nn * (OUT_CH / 2);  // 24 words per row
    for (int i = t; i < words; i += 512) {
        int r = i / (OUT_CH / 2);
        float d = sdinv[r];
        unsigned int u = gw[i];
        float lo = bf2f((ushort)(u & 0xffff)) * d;
        float hi = bf2f((ushort)(u >> 16)) * d;
        gw[i] = (unsigned int)f2bf(lo) | ((unsigned int)f2bf(hi) << 16);
    }
}

// ---------------------------------------------------------------------------
// k_gather: one thread per (node, 4-channel group). uint2 loads (4 bf16),
// 12 lanes per row; float4 coalesced store. NO fused stats (round-7 lesson).
// ---------------------------------------------------------------------------
__global__ __launch_bounds__(256) void k_gather(const int* __restrict__ sorted_src,
                                                const int* __restrict__ rowstart,
                                                const int* __restrict__ counts,
                                                const ushort* __restrict__ g,
                                                float* __restrict__ out, int N) {
    int t = blockIdx.x * blockDim.x + threadIdx.x;
    if (t >= N * 12) return;
    int node = t / 12;
    int sub = t - node * 12;          // 0..11 -> channels [4*sub, 4*sub+4)
    const uint2* gp = (const uint2*)g;  // row = 12 x uint2 (8B each)
    int cnt = counts[node];
    int e = rowstart[node];
    int end = e + cnt;

    uint2 sv = gp[(size_t)node * 12 + sub];  // self loop
    float a0 = bf2f((ushort)(sv.x & 0xffff));
    float a1 = bf2f((ushort)(sv.x >> 16));
    float a2 = bf2f((ushort)(sv.y & 0xffff));
    float a3 = bf2f((ushort)(sv.y >> 16));

    for (; e + 4 <= end; e += 4) {
        int s0 = sorted_src[e];
        int s1 = sorted_src[e + 1];
        int s2 = sorted_src[e + 2];
        int s3 = sorted_src[e + 3];
        uint2 v0 = gp[(size_t)s0 * 12 + sub];
        uint2 v1 = gp[(size_t)s1 * 12 + sub];
        uint2 v2 = gp[(size_t)s2 * 12 + sub];
        uint2 v3 = gp[(size_t)s3 * 12 + sub];
        a0 += bf2f((ushort)(v0.x & 0xffff)) + bf2f((ushort)(v1.x & 0xffff))
            + bf2f((ushort)(v2.x & 0xffff)) + bf2f((ushort)(v3.x & 0xffff));
        a1 += bf2f((ushort)(v0.x >> 16)) + bf2f((ushort)(v1.x >> 16))
            + bf2f((ushort)(v2.x >> 16)) + bf2f((ushort)(v3.x >> 16));
        a2 += bf2f((ushort)(v0.y & 0xffff)) + bf2f((ushort)(v1.y & 0xffff))
            + bf2f((ushort)(v2.y & 0xffff)) + bf2f((ushort)(v3.y & 0xffff));
        a3 += bf2f((ushort)(v0.y >> 16)) + bf2f((ushort)(v1.y >> 16))
            + bf2f((ushort)(v2.y >> 16)) + bf2f((ushort)(v3.y >> 16));
    }
    for (; e < end; ++e) {
        int s = sorted_src[e];
        uint2 v = gp[(size_t)s * 12 + sub];
        a0 += bf2f((ushort)(v.x & 0xffff));
        a1 += bf2f((ushort)(v.x >> 16));
        a2 += bf2f((ushort)(v.y & 0xffff));
        a3 += bf2f((ushort)(v.y >> 16));
    }
    float di = rsqrtf((float)cnt + 1.0f);
    float4 r;
    r.x = a0 * di; r.y = a1 * di; r.z = a2 * di; r.w = a3 * di;
    ((float4*)out)[(size_t)node * 12 + sub] = r;
}

// ---------------------------------------------------------------------------
// k_stats: per-channel sum and sum-of-squares of out (256 blocks only)
// ---------------------------------------------------------------------------
__global__ __launch_bounds__(768) void k_stats(const float* __restrict__ v,
                                               float* __restrict__ stats, int N) {
    __shared__ float ls[16][OUT_CH];
    __shared__ float ls2[16][OUT_CH];
    int c = threadIdx.x;   // 0..47
    int ty = threadIdx.y;  // 0..15
    float s = 0.f, s2 = 0.f;
    for (int r = blockIdx.x * 16 + ty; r < N; r += gridDim.x * 16) {
        float u = v[(size_t)r * OUT_CH + c];
        s += u;
        s2 += u * u;
    }
    ls[ty][c] = s;
    ls2[ty][c] = s2;
    __syncthreads();
    for (int h = 8; h > 0; h >>= 1) {
        if (ty < h) {
            ls[ty][c] += ls[ty + h][c];
            ls2[ty][c] += ls2[ty + h][c];
        }
        __syncthreads();
    }
    if (ty == 0) {
        atomicAdd(&stats[c], ls[0][c]);
        atomicAdd(&stats[OUT_CH + c], ls2[0][c]);
    }
}

// ---------------------------------------------------------------------------
// k_final: BN (batch stats) + ReLU, in place. GCN bias b cancels under BN.
// ---------------------------------------------------------------------------
__global__ void k_final(float* __restrict__ out, const float* __restrict__ stats,
                        const float* __restrict__ gamma,
                        const float* __restrict__ beta, int N) {
    int t = blockIdx.x * blockDim.x + threadIdx.x;
    int total = N * OUT_CH;
    if (t >= total) return;
    int c = t % OUT_CH;
    float invN = 1.0f / (float)N;
    float m = stats[c] * invN;
    float var = stats[OUT_CH + c] * invN - m * m;
    float y = (out[t] - m) * rsqrtf(var + BN_EPS) * gamma[c] + beta[c];
    out[t] = fmaxf(y, 0.0f);
}

extern "C" void kernel_launch(void* const* d_in, const int* in_sizes, int n_in,
                              void* d_out, int out_size, void* d_ws, size_t ws_size,
                              hipStream_t stream) {
    const float* x     = (const float*)d_in[0];
    const int*   ei    = (const int*)d_in[1];
    const float* W     = (const float*)d_in[2];
    // d_in[3] = b : constant per-channel offset cancels in BatchNorm -> unused
    const float* gamma = (const float*)d_in[4];
    const float* beta  = (const float*)d_in[5];
    float*       out   = (float*)d_out;

    int N = in_sizes[0] / IN_CH;     // 100000 (< 2^17 for packing)
    int E = in_sizes[1] / 2;         // 1600000
    const int* src = ei;             // edge_index[0]
    const int* dst = ei + E;         // edge_index[1]

    int nb = (N + NPB - 1) / NPB;    // 391 buckets

    // workspace layout (bytes):
    // [0, 512)          stats float[128]
    // [512, 2564)       bstart int[513]
    // [4096, 6144)      bcur int[512]
    // [8192, 10240)     bhist int[512]
    // [139264, +4N)     counts int[N]
    // [.., +4N)         rowstart int[N]
    // [.., +4E)         binned uint[E]
    // [.., +4E)         sorted_src int[E]
    // [.., +96N)        g bf16[N*48] (16B aligned)
    char* wsb = (char*)d_ws;
    float*        stats      = (float*)wsb;
    int*          bstart     = (int*)(wsb + 512);
    int*          bcur       = (int*)(wsb + 4096);
    int*          bhist      = (int*)(wsb + 8192);
    size_t A = 139264;
    int*          counts     = (int*)(wsb + A);
    int*          rowstart   = (int*)(wsb + A + (size_t)4 * N);
    unsigned int* binned     = (unsigned int*)(wsb + A + (size_t)8 * N);
    int*          sorted_src = (int*)(wsb + A + (size_t)8 * N + (size_t)4 * E);
    ushort*       g          = (ushort*)(wsb + A + (size_t)8 * N + (size_t)8 * E);

    int b = 256;
    int nchunks = (E + CHUNK - 1) / CHUNK;   // 391
    int ngemm = (N + b - 1) / b;             // 391

    // 1. zero bhist
    k_zero<<<1, 512, 0, stream>>>(bhist);
    // 2. bucket histogram (512 blocks, LDS hist, atomic flush)
    k_binhist<<<NHB, b, 0, stream>>>(dst, bhist, E);
    // 3. reduce + scan -> bstart / bcur; zero stats
    k_scanb<<<1, b, 0, stream>>>(bhist, bstart, bcur, nb, stats);
    // 4. fused: coarse counting-sort (blocks 0..nchunks) + unscaled GEMM (rest)
    k_binmm<<<nchunks + ngemm, b, 0, stream>>>(src, dst, bcur, binned, E, nchunks,
                                               x, W, g, N);
    // 5. fine sort within buckets -> counts/rowstart/sorted_src + g rescale
    k_fine<<<nb, 512, 0, stream>>>(binned, bstart, counts, rowstart, sorted_src, g, N);
    // 6. gather + self loop + dst dinv (4 channels per thread)
    int gthreads = N * 12;
    k_gather<<<(gthreads + b - 1) / b, b, 0, stream>>>(sorted_src, rowstart, counts, g, out, N);
    // 7. BN stats
    dim3 sblk(OUT_CH, 16);
    k_stats<<<256, sblk, 0, stream>>>(out, stats, N);
    // 8. BN + ReLU in place
    int totalT = N * OUT_CH;
    k_final<<<(totalT + b - 1) / b, b, 0, stream>>>(out, stats, gamma, beta, N);
}